// Round 9
// baseline (214.337 us; speedup 1.0000x reference)
//
#include <hip/hip_runtime.h>
#include <hip/hip_bf16.h>
#include <stdint.h>

typedef float v4f __attribute__((ext_vector_type(4)));
typedef short v8s __attribute__((ext_vector_type(8)));

#define LOG2E 1.44269504088896f
#define QSCALE (0.125f * LOG2E)   // fold softmax log2-domain into Q pre-scale
#define SOFTMAX_OFF 16.0f         // fixed softmax offset (exact; cancels in O/l)

__device__ __forceinline__ unsigned short f2bf(float f) {
    unsigned int u = __float_as_uint(f);
    u += 0x7fffu + ((u >> 16) & 1u);          // RTNE
    return (unsigned short)(u >> 16);
}

// Compiler+HW LDS ordering fence for the intra-wave P exchange.
#define LDS_FENCE() __builtin_amdgcn_fence(__ATOMIC_ACQ_REL, "workgroup")

// async global->LDS, 16B per lane, LDS dest = wave-uniform base + lane*16
__device__ __forceinline__ void gload_lds16(const unsigned short* g, unsigned short* s) {
    __builtin_amdgcn_global_load_lds(
        (const __attribute__((address_space(1))) unsigned int*)g,
        (__attribute__((address_space(3))) unsigned int*)s, 16, 0, 0);
}

// ---------------- elementwise f32 -> bf16 (x4 vectorized) ----------------
__global__ void k_cast_bf16(const float* __restrict__ src,
                            unsigned short* __restrict__ dst, int n4) {
    int i = blockIdx.x * blockDim.x + threadIdx.x;
    int stride = gridDim.x * blockDim.x;
    for (; i < n4; i += stride) {
        float4 v = ((const float4*)src)[i];
        ushort4 o;
        o.x = f2bf(v.x); o.y = f2bf(v.y); o.z = f2bf(v.z); o.w = f2bf(v.w);
        ((ushort4*)dst)[i] = o;
    }
}

// ------- both weight transposes in one launch: f32 [K][N] -> bf16 [N][K] -------
__global__ void k_transpose_both(const float* __restrict__ w_qkv,
                                 const float* __restrict__ w_out,
                                 unsigned short* __restrict__ wqkvT,
                                 unsigned short* __restrict__ woutT) {
    __shared__ unsigned short tile[64][65];
    int id = blockIdx.x;
    const float* src; unsigned short* dst; int N, kb, nb;
    if (id < 768) { src = w_qkv; dst = wqkvT; N = 3072; nb = (id % 48) * 64; kb = (id / 48) * 64; }
    else { id -= 768; src = w_out; dst = woutT; N = 1024; nb = (id % 16) * 64; kb = (id / 16) * 64; }
    const int K = 1024;
    int t = threadIdx.x;
    for (int i = 0; i < 16; ++i) {
        int e = t + i * 256;
        int n_l = e & 63, k_l = e >> 6;
        tile[n_l][k_l] = f2bf(src[(size_t)(kb + k_l) * N + nb + n_l]);
    }
    __syncthreads();
    for (int i = 0; i < 16; ++i) {
        int e = t + i * 256;
        int k_l = e & 63, n_l = e >> 6;
        dst[(size_t)(nb + n_l) * K + kb + k_l] = tile[n_l][k_l];
    }
}

// ------------- QKV GEMM with fused RoPE/split epilogue -------------
// C = xb[4096][1024] @ wqkvT[3072][1024]^T. Each wave's 64-col span is
// exactly one head (64-aligned regions). RoPE pair (d, d+32) lives in
// acc[i][j] / acc[i][j+2] of the same wave -> rotate in epilogue, write
// Qg (pre-scaled by QSCALE), Kg, Vg as [BH][S][64] bf16 directly.
__global__ __launch_bounds__(256) void k_gemm_qkv(
    const unsigned short* __restrict__ A,    // xb  [4096][1024]
    const unsigned short* __restrict__ Bt,   // wqkvT [3072][1024]
    unsigned short* __restrict__ Qg,
    unsigned short* __restrict__ Kg,
    unsigned short* __restrict__ Vg) {
    const int K = 1024, N = 3072;
    __shared__ __align__(16) unsigned short Ab[128 * 32];
    __shared__ __align__(16) unsigned short Bb[128 * 32];
    const int t = threadIdx.x;
    const int w = t >> 6, l = t & 63, quad = l >> 4, ln = l & 15;
    const int wm = (w >> 1) * 64, wn = (w & 1) * 64;
    const int mb = blockIdx.y * 128, nb = blockIdx.x * 128;

    v4f acc[4][4];
#pragma unroll
    for (int i = 0; i < 4; ++i)
#pragma unroll
        for (int j = 0; j < 4; ++j) acc[i][j] = (v4f){0.f, 0.f, 0.f, 0.f};

    for (int k0 = 0; k0 < K; k0 += 32) {
        __syncthreads();
#pragma unroll
        for (int u = 0; u < 2; ++u) {
            int e = t + u * 256;                       // slot id, 16B each
            gload_lds16(A + (size_t)(mb + (e >> 2)) * K + k0 + (e & 3) * 8,
                        &Ab[(size_t)(w * 64 + u * 256) * 8]);
            gload_lds16(Bt + (size_t)(nb + (e >> 2)) * K + k0 + (e & 3) * 8,
                        &Bb[(size_t)(w * 64 + u * 256) * 8]);
        }
        __syncthreads();
        v8s af[4], bfr[4];
#pragma unroll
        for (int i = 0; i < 4; ++i)
            af[i] = *(const v8s*)&Ab[(wm + i * 16 + ln) * 32 + quad * 8];
#pragma unroll
        for (int j = 0; j < 4; ++j)
            bfr[j] = *(const v8s*)&Bb[(wn + j * 16 + ln) * 32 + quad * 8];
#pragma unroll
        for (int i = 0; i < 4; ++i)
#pragma unroll
            for (int j = 0; j < 4; ++j)
                acc[i][j] = __builtin_amdgcn_mfma_f32_16x16x32_bf16(
                    af[i], bfr[j], acc[i][j], 0, 0, 0);
    }

    // ---- fused epilogue ----
    const int col0 = nb + wn;                 // wave's first col (mult of 64)
    const int region = col0 >> 10;            // 0=Q, 1=K, 2=V
    const int h = (col0 & 1023) >> 6;         // head within region
    unsigned short* dst = (region == 0) ? Qg : (region == 1) ? Kg : Vg;

    if (region == 2) {                        // V: plain cast + write
#pragma unroll
        for (int i = 0; i < 4; ++i)
#pragma unroll
            for (int r = 0; r < 4; ++r) {
                int row = mb + wm + i * 16 + quad * 4 + r;
                int s = row & 2047, b = row >> 11;
                size_t base = ((size_t)(b * 16 + h) * 2048 + s) * 64;
#pragma unroll
                for (int j = 0; j < 4; ++j)
                    dst[base + j * 16 + ln] = f2bf(acc[i][j][r]);
            }
    } else {                                  // Q/K: RoPE rotate pairs (d, d+32)
        const float scale = (region == 0) ? QSCALE : 1.0f;
#pragma unroll
        for (int jj = 0; jj < 2; ++jj) {
            float inv = __expf(-(float)(jj * 16 + ln) * 0.28782313662425572f);
#pragma unroll
            for (int i = 0; i < 4; ++i)
#pragma unroll
                for (int r = 0; r < 4; ++r) {
                    int row = mb + wm + i * 16 + quad * 4 + r;
                    int s = row & 2047, b = row >> 11;
                    float sn, cs;
                    sincosf((float)s * inv, &sn, &cs);
                    float t1 = acc[i][jj][r], t2 = acc[i][jj + 2][r];
                    size_t base = ((size_t)(b * 16 + h) * 2048 + s) * 64;
                    dst[base + jj * 16 + ln]      = f2bf((t1 * cs - t2 * sn) * scale);
                    dst[base + jj * 16 + ln + 32] = f2bf((t2 * cs + t1 * sn) * scale);
                }
        }
    }
}

// ------------- V transpose: bf16 [BH][S][64] -> [BH][64][S] -------------
__global__ void k_vtrans(const unsigned short* __restrict__ Vg,
                         unsigned short* __restrict__ Vt) {
    __shared__ unsigned short vtile[64][65];
    const int bh = blockIdx.y, sb = blockIdx.x * 64;
    const int t = threadIdx.x;
    const unsigned short* src = Vg + (size_t)bh * 2048 * 64;
    for (int i = 0; i < 16; ++i) {
        int e = t + i * 256;
        int d = e & 63, s_l = e >> 6;
        vtile[d][s_l] = src[(size_t)(sb + s_l) * 64 + d];
    }
    __syncthreads();
    for (int i = 0; i < 16; ++i) {
        int e = t + i * 256;
        int s_l = e & 63, d = e >> 6;
        Vt[(size_t)(bh * 64 + d) * 2048 + sb + s_l] = vtile[d][s_l];
    }
}

// ------------- generic GEMM (used for the output projection) -------------
template<bool BF16OUT>
__global__ __launch_bounds__(256) void k_gemm_bt(
    const unsigned short* __restrict__ A,
    const unsigned short* __restrict__ Bt,
    void* __restrict__ Cv, int M, int N, int K) {
    __shared__ __align__(16) unsigned short Ab[128 * 32];
    __shared__ __align__(16) unsigned short Bb[128 * 32];
    const int t = threadIdx.x;
    const int w = t >> 6, l = t & 63, quad = l >> 4, ln = l & 15;
    const int wm = (w >> 1) * 64, wn = (w & 1) * 64;
    const int mb = blockIdx.y * 128, nb = blockIdx.x * 128;

    v4f acc[4][4];
#pragma unroll
    for (int i = 0; i < 4; ++i)
#pragma unroll
        for (int j = 0; j < 4; ++j) acc[i][j] = (v4f){0.f, 0.f, 0.f, 0.f};

    for (int k0 = 0; k0 < K; k0 += 32) {
        __syncthreads();
#pragma unroll
        for (int u = 0; u < 2; ++u) {
            int e = t + u * 256;
            gload_lds16(A + (size_t)(mb + (e >> 2)) * K + k0 + (e & 3) * 8,
                        &Ab[(size_t)(w * 64 + u * 256) * 8]);
            gload_lds16(Bt + (size_t)(nb + (e >> 2)) * K + k0 + (e & 3) * 8,
                        &Bb[(size_t)(w * 64 + u * 256) * 8]);
        }
        __syncthreads();
        v8s af[4], bfr[4];
#pragma unroll
        for (int i = 0; i < 4; ++i)
            af[i] = *(const v8s*)&Ab[(wm + i * 16 + ln) * 32 + quad * 8];
#pragma unroll
        for (int j = 0; j < 4; ++j)
            bfr[j] = *(const v8s*)&Bb[(wn + j * 16 + ln) * 32 + quad * 8];
#pragma unroll
        for (int i = 0; i < 4; ++i)
#pragma unroll
            for (int j = 0; j < 4; ++j)
                acc[i][j] = __builtin_amdgcn_mfma_f32_16x16x32_bf16(
                    af[i], bfr[j], acc[i][j], 0, 0, 0);
    }

#pragma unroll
    for (int i = 0; i < 4; ++i) {
        int r0 = mb + wm + i * 16 + quad * 4;
#pragma unroll
        for (int j = 0; j < 4; ++j) {
            int c0 = nb + wn + j * 16 + ln;
#pragma unroll
            for (int r = 0; r < 4; ++r) {
                if (BF16OUT)
                    ((unsigned short*)Cv)[(size_t)(r0 + r) * N + c0] = f2bf(acc[i][j][r]);
                else
                    ((float*)Cv)[(size_t)(r0 + r) * N + c0] = acc[i][j][r];
            }
        }
    }
}

// ------------- causal flash attention, v8 (unchanged from round 8) -------------
__global__ __launch_bounds__(256) void k_flash(
    const unsigned short* __restrict__ Qg,   // [BH][S][64], scaled 0.125*log2e
    const unsigned short* __restrict__ Kg,   // [BH][S][64]
    const unsigned short* __restrict__ Vt,   // [BH][64][S]
    unsigned short* __restrict__ Og) {       // [B*S][1024]
    __shared__ __align__(16) unsigned short Kb[2][64 * 64];
    __shared__ __align__(16) unsigned short Vb[2][64 * 64];
    __shared__ __align__(16) unsigned short P[4][16][72];

    const int id = blockIdx.x;
    const int xcd = id & 7, slot = id >> 3;
    const int bh = xcd * 4 + (slot & 3);
    const int qt = 31 - (slot >> 2);                 // heavy tiles first
    const int qbase = qt * 64;
    const int nit = qt + 1;

    const int t = threadIdx.x, w = t >> 6, l = t & 63, quad = l >> 4, ln = l & 15;
    const int b = bh >> 4, h = bh & 15;

    const unsigned short* Qp = Qg + (size_t)bh * 2048 * 64;
    const unsigned short* Kp = Kg + (size_t)bh * 2048 * 64;
    const unsigned short* Vp = Vt + (size_t)bh * 64 * 2048;

    unsigned kst[2], vst[2];
    int cchunk = l & 7, rloc = l >> 3;
#pragma unroll
    for (int j = 0; j < 2; ++j) {
        int c = w + j * 4;
        int rr = c * 8 + rloc;
        int g = (cchunk + rr) & 7;
        kst[j] = (unsigned)(rr * 64 + g * 8);
        vst[j] = (unsigned)(rr * 2048 + g * 8);
    }
    const int c0 = ((quad - ln) & 7) * 8;
    const int c1 = ((quad + 4 - ln) & 7) * 8;
    const v8s ones = {0x3F80, 0x3F80, 0x3F80, 0x3F80, 0x3F80, 0x3F80, 0x3F80, 0x3F80};

    const int qrow = qbase + w * 16 + ln;
    v8s qf0 = *(const v8s*)(Qp + (size_t)qrow * 64 + quad * 8);
    v8s qf1 = *(const v8s*)(Qp + (size_t)qrow * 64 + quad * 8 + 32);

    v4f oacc[5];
#pragma unroll
    for (int dt = 0; dt < 5; ++dt) oacc[dt] = (v4f){0.f, 0.f, 0.f, 0.f};

    auto stage = [&](int buf, int kvb) {
        const unsigned short* kg = Kp + (size_t)kvb * 64;
        const unsigned short* vg = Vp + kvb;
#pragma unroll
        for (int j = 0; j < 2; ++j) {
            int c = w + j * 4;
            gload_lds16(kg + kst[j], &Kb[buf][c * 512]);
            gload_lds16(vg + vst[j], &Vb[buf][c * 512]);
        }
    };

    auto compute = [&](int buf, int it) {
        v4f sc[4];
#pragma unroll
        for (int kt = 0; kt < 4; ++kt) {
            int row = kt * 16 + ln;
            v8s k0 = *(const v8s*)&Kb[buf][row * 64 + c0];
            v8s k1 = *(const v8s*)&Kb[buf][row * 64 + c1];
            sc[kt] = (v4f){0.f, 0.f, 0.f, 0.f};
            sc[kt] = __builtin_amdgcn_mfma_f32_16x16x32_bf16(qf0, k0, sc[kt], 0, 0, 0);
            sc[kt] = __builtin_amdgcn_mfma_f32_16x16x32_bf16(qf1, k1, sc[kt], 0, 0, 0);
        }
        if (it == qt) {
            int q0 = qbase + w * 16 + quad * 4;
#pragma unroll
            for (int kt = 0; kt < 4; ++kt) {
                int kv = qbase + kt * 16 + ln;
#pragma unroll
                for (int r = 0; r < 4; ++r)
                    if (kv > q0 + r) sc[kt][r] = -1e30f;
            }
        }
#pragma unroll
        for (int kt = 0; kt < 4; ++kt)
#pragma unroll
            for (int r = 0; r < 4; ++r)
                sc[kt][r] = exp2f(sc[kt][r] - SOFTMAX_OFF);

#pragma unroll
        for (int kt = 0; kt < 4; ++kt) {
            union { __hip_bfloat162 hh; unsigned int u; } p01, p23;
            p01.hh = __float22bfloat162_rn(make_float2(sc[kt][0], sc[kt][1]));
            p23.hh = __float22bfloat162_rn(make_float2(sc[kt][2], sc[kt][3]));
            P[w][quad * 4 + 0][kt * 16 + ln] = (unsigned short)p01.u;
            P[w][quad * 4 + 1][kt * 16 + ln] = (unsigned short)(p01.u >> 16);
            P[w][quad * 4 + 2][kt * 16 + ln] = (unsigned short)p23.u;
            P[w][quad * 4 + 3][kt * 16 + ln] = (unsigned short)(p23.u >> 16);
        }
        LDS_FENCE();
        v8s pf0 = *(const v8s*)&P[w][ln][quad * 8];
        v8s pf1 = *(const v8s*)&P[w][ln][quad * 8 + 32];
        LDS_FENCE();
#pragma unroll
        for (int dt = 0; dt < 4; ++dt) {
            int row = dt * 16 + ln;
            v8s v0 = *(const v8s*)&Vb[buf][row * 64 + c0];
            v8s v1 = *(const v8s*)&Vb[buf][row * 64 + c1];
            oacc[dt] = __builtin_amdgcn_mfma_f32_16x16x32_bf16(pf0, v0, oacc[dt], 0, 0, 0);
            oacc[dt] = __builtin_amdgcn_mfma_f32_16x16x32_bf16(pf1, v1, oacc[dt], 0, 0, 0);
        }
        oacc[4] = __builtin_amdgcn_mfma_f32_16x16x32_bf16(pf0, ones, oacc[4], 0, 0, 0);
        oacc[4] = __builtin_amdgcn_mfma_f32_16x16x32_bf16(pf1, ones, oacc[4], 0, 0, 0);
    };

    stage(0, 0);
    int it = 0;
    for (;;) {
        __syncthreads();
        stage(1, (it + 1) * 64);
        compute(0, it);
        if (++it >= nit) break;
        __syncthreads();
        stage(0, (it + 1) * 64);
        compute(1, it);
        if (++it >= nit) break;
    }

    float rden[4];
#pragma unroll
    for (int r = 0; r < 4; ++r) rden[r] = 1.f / oacc[4][r];
#pragma unroll
    for (int dt = 0; dt < 4; ++dt)
#pragma unroll
        for (int r = 0; r < 4; ++r) {
            int s = qbase + w * 16 + quad * 4 + r;
            Og[(size_t)(b * 2048 + s) * 1024 + h * 64 + dt * 16 + ln] =
                f2bf(oacc[dt][r] * rden[r]);
        }
}

extern "C" void kernel_launch(void* const* d_in, const int* in_sizes, int n_in,
                              void* d_out, int out_size, void* d_ws, size_t ws_size,
                              hipStream_t stream) {
    const float* x     = (const float*)d_in[0];
    const float* w_qkv = (const float*)d_in[2];
    const float* w_out = (const float*)d_in[3];
    char* ws = (char*)d_ws;

    unsigned short* xb    = (unsigned short*)(ws);                      //  8 MB
    unsigned short* wqkvT = (unsigned short*)(ws + (size_t)(8 << 20));  //  6 MB
    unsigned short* woutT = (unsigned short*)(ws + (size_t)(14 << 20)); //  2 MB
    unsigned short* Qg    = (unsigned short*)(ws + (size_t)(16 << 20)); //  8 MB
    unsigned short* Kg    = (unsigned short*)(ws + (size_t)(24 << 20)); //  8 MB (K over-prefetch -> Vg)
    unsigned short* Vg    = (unsigned short*)(ws + (size_t)(32 << 20)); //  8 MB
    unsigned short* Vt    = (unsigned short*)(ws + (size_t)(40 << 20)); //  8 MB (V over-prefetch -> Og)
    unsigned short* Og    = (unsigned short*)(ws + (size_t)(48 << 20)); //  8 MB

    k_cast_bf16<<<1024, 256, 0, stream>>>(x, xb, 4096 * 1024 / 4);
    k_transpose_both<<<1024, 256, 0, stream>>>(w_qkv, w_out, wqkvT, woutT);
    k_gemm_qkv<<<dim3(24, 32), 256, 0, stream>>>(xb, wqkvT, Qg, Kg, Vg);
    k_vtrans<<<dim3(32, 32), 256, 0, stream>>>(Vg, Vt);
    k_flash<<<1024, 256, 0, stream>>>(Qg, Kg, Vt, Og);
    k_gemm_bt<false><<<dim3(8, 32), 256, 0, stream>>>(Og, woutT, (float*)d_out, 4096, 1024, 1024);
}

// Round 10
// 196.655 us; speedup vs baseline: 1.0899x; 1.0899x over previous
//
#include <hip/hip_runtime.h>
#include <hip/hip_bf16.h>
#include <stdint.h>

typedef float v4f __attribute__((ext_vector_type(4)));
typedef short v8s __attribute__((ext_vector_type(8)));

#define LOG2E 1.44269504088896f
#define QSCALE (0.125f * LOG2E)   // fold softmax log2-domain into Q pre-scale
#define SOFTMAX_OFF 16.0f         // fixed softmax offset (exact; cancels in O/l)

__device__ __forceinline__ unsigned short f2bf(float f) {
    unsigned int u = __float_as_uint(f);
    u += 0x7fffu + ((u >> 16) & 1u);          // RTNE
    return (unsigned short)(u >> 16);
}

// Compiler+HW LDS ordering fence for the intra-wave P exchange.
#define LDS_FENCE() __builtin_amdgcn_fence(__ATOMIC_ACQ_REL, "workgroup")

// async global->LDS, 16B per lane, LDS dest = wave-uniform base + lane*16
__device__ __forceinline__ void gload_lds16(const unsigned short* g, unsigned short* s) {
    __builtin_amdgcn_global_load_lds(
        (const __attribute__((address_space(1))) unsigned int*)g,
        (__attribute__((address_space(3))) unsigned int*)s, 16, 0, 0);
}

// ---------------- prep: cast + rope table + both weight transposes ----------------
// blocks [0,1024): x f32->bf16 (4 float4/thread)
// blocks [1024,1280): rope table (cos,sin)[2048][32]
// blocks [1280,2048): w_qkv transpose+cast;  [2048,2304): w_out transpose+cast
__global__ void k_prep(const float* __restrict__ x,
                       const float* __restrict__ w_qkv,
                       const float* __restrict__ w_out,
                       unsigned short* __restrict__ xb,
                       unsigned short* __restrict__ wqkvT,
                       unsigned short* __restrict__ woutT,
                       float2* __restrict__ rope) {
    __shared__ unsigned short tile[64][65];
    int id = blockIdx.x, t = threadIdx.x;
    if (id < 1024) {
        int base = id * 256 + t;
#pragma unroll
        for (int k = 0; k < 4; ++k) {
            int i = base + k * 262144;
            float4 v = ((const float4*)x)[i];
            ushort4 o;
            o.x = f2bf(v.x); o.y = f2bf(v.y); o.z = f2bf(v.z); o.w = f2bf(v.w);
            ((ushort4*)xb)[i] = o;
        }
        return;
    }
    id -= 1024;
    if (id < 256) {
        int idx = id * 256 + t;                    // 65536 = 2048 s x 32 d
        int s = idx >> 5, d = idx & 31;
        float inv = __expf(-(float)d * 0.28782313662425572f);  // 10000^(-d/32)
        float sn, cs;
        sincosf((float)s * inv, &sn, &cs);
        rope[idx] = make_float2(cs, sn);
        return;
    }
    id -= 256;
    const float* src; unsigned short* dst; int N, kb, nb;
    if (id < 768) { src = w_qkv; dst = wqkvT; N = 3072; nb = (id % 48) * 64; kb = (id / 48) * 64; }
    else { id -= 768; src = w_out; dst = woutT; N = 1024; nb = (id % 16) * 64; kb = (id / 16) * 64; }
    const int K = 1024;
    for (int i = 0; i < 16; ++i) {
        int e = t + i * 256;
        int n_l = e & 63, k_l = e >> 6;
        tile[n_l][k_l] = f2bf(src[(size_t)(kb + k_l) * N + nb + n_l]);
    }
    __syncthreads();
    for (int i = 0; i < 16; ++i) {
        int e = t + i * 256;
        int k_l = e & 63, n_l = e >> 6;
        dst[(size_t)(nb + n_l) * K + kb + k_l] = tile[n_l][k_l];
    }
}

// ------------- QKV GEMM, single-barrier dbuf, fused RoPE + V-transpose -------------
// C = xb[4096][1024] @ wqkvT[3072][1024]^T. Blocks are region-pure:
// nb<1024 Q, <2048 K (rope epilogue via table), >=2048 V (LDS-transpose
// epilogue writing Vt[bh][64][2048] directly; reuses staging LDS).
__global__ __launch_bounds__(256) void k_gemm_qkv(
    const unsigned short* __restrict__ A,
    const unsigned short* __restrict__ Bt,
    const float2* __restrict__ rope,
    unsigned short* __restrict__ Qg,
    unsigned short* __restrict__ Kg,
    unsigned short* __restrict__ Vt) {
    const int K = 1024;
    __shared__ __align__(16) union {
        struct { unsigned short Ab[2][4096], Bb[2][4096]; } g;   // 32 KB dbuf
        unsigned short vt[2][64][136];                           // 34 KB V-transpose
    } sm;
    const int t = threadIdx.x;
    const int w = t >> 6, l = t & 63, quad = l >> 4, ln = l & 15;
    const int wm = (w >> 1) * 64, wn = (w & 1) * 64;
    const int mb = blockIdx.y * 128, nb = blockIdx.x * 128;

    v4f acc[4][4];
#pragma unroll
    for (int i = 0; i < 4; ++i)
#pragma unroll
        for (int j = 0; j < 4; ++j) acc[i][j] = (v4f){0.f, 0.f, 0.f, 0.f};

    auto stage = [&](int buf, int k0) {
#pragma unroll
        for (int u = 0; u < 2; ++u) {
            int e = t + u * 256;                   // slot id, 16B each
            gload_lds16(A + (size_t)(mb + (e >> 2)) * K + k0 + (e & 3) * 8,
                        &sm.g.Ab[buf][(w * 64 + u * 256) * 8]);
            gload_lds16(Bt + (size_t)(nb + (e >> 2)) * K + k0 + (e & 3) * 8,
                        &sm.g.Bb[buf][(w * 64 + u * 256) * 8]);
        }
    };

    stage(0, 0);
    int buf = 0;
    for (int itk = 0; itk < 32; ++itk) {
        __syncthreads();                           // buf's staging landed
        if (itk + 1 < 32) stage(buf ^ 1, (itk + 1) * 32);
        v8s af[4], bfr[4];
#pragma unroll
        for (int i = 0; i < 4; ++i)
            af[i] = *(const v8s*)&sm.g.Ab[buf][(wm + i * 16 + ln) * 32 + quad * 8];
#pragma unroll
        for (int j = 0; j < 4; ++j)
            bfr[j] = *(const v8s*)&sm.g.Bb[buf][(wn + j * 16 + ln) * 32 + quad * 8];
#pragma unroll
        for (int i = 0; i < 4; ++i)
#pragma unroll
            for (int j = 0; j < 4; ++j)
                acc[i][j] = __builtin_amdgcn_mfma_f32_16x16x32_bf16(
                    af[i], bfr[j], acc[i][j], 0, 0, 0);
        buf ^= 1;
    }

    if (nb >= 2048) {                              // ---- V: LDS transpose epilogue
        __syncthreads();                           // all staging reads done; reuse LDS
        const int hh = wn >> 6;
#pragma unroll
        for (int i = 0; i < 4; ++i)
#pragma unroll
            for (int j = 0; j < 4; ++j) {
                int d = j * 16 + ln;
#pragma unroll
                for (int r = 0; r < 4; ++r)
                    sm.vt[hh][d][wm + i * 16 + quad * 4 + r] = f2bf(acc[i][j][r]);
            }
        __syncthreads();
        const int hbase = (nb & 1023) >> 6;
        const int b = mb >> 11, sbase = mb & 2047;
#pragma unroll
        for (int i = 0; i < 8; ++i) {
            int c = t + i * 256;                   // 2048 chunks of 16B
            int h2 = c >> 10, dd = (c >> 4) & 63, off = (c & 15) * 8;
            v8s val = *(const v8s*)&sm.vt[h2][dd][off];
            *(v8s*)(Vt + ((size_t)((b * 16 + hbase + h2) * 64 + dd) * 2048 + sbase + off)) = val;
        }
        return;
    }

    // ---- Q/K: rope epilogue via table
    const int region = (nb + wn) >> 10;            // 0=Q, 1=K
    const int h = ((nb + wn) & 1023) >> 6;
    unsigned short* dst = region == 0 ? Qg : Kg;
    const float scale = region == 0 ? QSCALE : 1.0f;
#pragma unroll
    for (int jj = 0; jj < 2; ++jj) {
        const float2* rp = rope + jj * 16 + ln;
#pragma unroll
        for (int i = 0; i < 4; ++i)
#pragma unroll
            for (int r = 0; r < 4; ++r) {
                int row = mb + wm + i * 16 + quad * 4 + r;
                int s = row & 2047, b = row >> 11;
                float2 cs = rp[s * 32];
                float t1 = acc[i][jj][r], t2 = acc[i][jj + 2][r];
                size_t base = ((size_t)(b * 16 + h) * 2048 + s) * 64;
                dst[base + jj * 16 + ln]      = f2bf((t1 * cs.x - t2 * cs.y) * scale);
                dst[base + jj * 16 + ln + 32] = f2bf((t2 * cs.x + t1 * cs.y) * scale);
            }
    }
}

// ------------- output projection GEMM, single-barrier dbuf, f32 out -------------
__global__ __launch_bounds__(256) void k_gemm_out(
    const unsigned short* __restrict__ A,      // Og [4096][1024]
    const unsigned short* __restrict__ Bt,     // woutT [1024][1024]
    float* __restrict__ C) {
    const int K = 1024, N = 1024;
    __shared__ __align__(16) unsigned short Ab[2][4096];
    __shared__ __align__(16) unsigned short Bb[2][4096];
    const int t = threadIdx.x;
    const int w = t >> 6, l = t & 63, quad = l >> 4, ln = l & 15;
    const int wm = (w >> 1) * 64, wn = (w & 1) * 64;
    const int mb = blockIdx.y * 128, nb = blockIdx.x * 128;

    v4f acc[4][4];
#pragma unroll
    for (int i = 0; i < 4; ++i)
#pragma unroll
        for (int j = 0; j < 4; ++j) acc[i][j] = (v4f){0.f, 0.f, 0.f, 0.f};

    auto stage = [&](int buf, int k0) {
#pragma unroll
        for (int u = 0; u < 2; ++u) {
            int e = t + u * 256;
            gload_lds16(A + (size_t)(mb + (e >> 2)) * K + k0 + (e & 3) * 8,
                        &Ab[buf][(w * 64 + u * 256) * 8]);
            gload_lds16(Bt + (size_t)(nb + (e >> 2)) * K + k0 + (e & 3) * 8,
                        &Bb[buf][(w * 64 + u * 256) * 8]);
        }
    };

    stage(0, 0);
    int buf = 0;
    for (int itk = 0; itk < 32; ++itk) {
        __syncthreads();
        if (itk + 1 < 32) stage(buf ^ 1, (itk + 1) * 32);
        v8s af[4], bfr[4];
#pragma unroll
        for (int i = 0; i < 4; ++i)
            af[i] = *(const v8s*)&Ab[buf][(wm + i * 16 + ln) * 32 + quad * 8];
#pragma unroll
        for (int j = 0; j < 4; ++j)
            bfr[j] = *(const v8s*)&Bb[buf][(wn + j * 16 + ln) * 32 + quad * 8];
#pragma unroll
        for (int i = 0; i < 4; ++i)
#pragma unroll
            for (int j = 0; j < 4; ++j)
                acc[i][j] = __builtin_amdgcn_mfma_f32_16x16x32_bf16(
                    af[i], bfr[j], acc[i][j], 0, 0, 0);
        buf ^= 1;
    }

#pragma unroll
    for (int i = 0; i < 4; ++i) {
        int r0 = mb + wm + i * 16 + quad * 4;
#pragma unroll
        for (int j = 0; j < 4; ++j) {
            int c0 = nb + wn + j * 16 + ln;
#pragma unroll
            for (int r = 0; r < 4; ++r)
                C[(size_t)(r0 + r) * N + c0] = acc[i][j][r];
        }
    }
}

// ------------- causal flash attention, v8 (unchanged from round 8) -------------
__global__ __launch_bounds__(256) void k_flash(
    const unsigned short* __restrict__ Qg,   // [BH][S][64], scaled 0.125*log2e
    const unsigned short* __restrict__ Kg,   // [BH][S][64]
    const unsigned short* __restrict__ Vt,   // [BH][64][S]
    unsigned short* __restrict__ Og) {       // [B*S][1024]
    __shared__ __align__(16) unsigned short Kb[2][64 * 64];
    __shared__ __align__(16) unsigned short Vb[2][64 * 64];
    __shared__ __align__(16) unsigned short P[4][16][72];

    const int id = blockIdx.x;
    const int xcd = id & 7, slot = id >> 3;
    const int bh = xcd * 4 + (slot & 3);
    const int qt = 31 - (slot >> 2);                 // heavy tiles first
    const int qbase = qt * 64;
    const int nit = qt + 1;

    const int t = threadIdx.x, w = t >> 6, l = t & 63, quad = l >> 4, ln = l & 15;
    const int b = bh >> 4, h = bh & 15;

    const unsigned short* Qp = Qg + (size_t)bh * 2048 * 64;
    const unsigned short* Kp = Kg + (size_t)bh * 2048 * 64;
    const unsigned short* Vp = Vt + (size_t)bh * 64 * 2048;

    unsigned kst[2], vst[2];
    int cchunk = l & 7, rloc = l >> 3;
#pragma unroll
    for (int j = 0; j < 2; ++j) {
        int c = w + j * 4;
        int rr = c * 8 + rloc;
        int g = (cchunk + rr) & 7;
        kst[j] = (unsigned)(rr * 64 + g * 8);
        vst[j] = (unsigned)(rr * 2048 + g * 8);
    }
    const int c0 = ((quad - ln) & 7) * 8;
    const int c1 = ((quad + 4 - ln) & 7) * 8;
    const v8s ones = {0x3F80, 0x3F80, 0x3F80, 0x3F80, 0x3F80, 0x3F80, 0x3F80, 0x3F80};

    const int qrow = qbase + w * 16 + ln;
    v8s qf0 = *(const v8s*)(Qp + (size_t)qrow * 64 + quad * 8);
    v8s qf1 = *(const v8s*)(Qp + (size_t)qrow * 64 + quad * 8 + 32);

    v4f oacc[5];
#pragma unroll
    for (int dt = 0; dt < 5; ++dt) oacc[dt] = (v4f){0.f, 0.f, 0.f, 0.f};

    auto stage = [&](int buf, int kvb) {
        const unsigned short* kg = Kp + (size_t)kvb * 64;
        const unsigned short* vg = Vp + kvb;
#pragma unroll
        for (int j = 0; j < 2; ++j) {
            int c = w + j * 4;
            gload_lds16(kg + kst[j], &Kb[buf][c * 512]);
            gload_lds16(vg + vst[j], &Vb[buf][c * 512]);
        }
    };

    auto compute = [&](int buf, int it) {
        v4f sc[4];
#pragma unroll
        for (int kt = 0; kt < 4; ++kt) {
            int row = kt * 16 + ln;
            v8s k0 = *(const v8s*)&Kb[buf][row * 64 + c0];
            v8s k1 = *(const v8s*)&Kb[buf][row * 64 + c1];
            sc[kt] = (v4f){0.f, 0.f, 0.f, 0.f};
            sc[kt] = __builtin_amdgcn_mfma_f32_16x16x32_bf16(qf0, k0, sc[kt], 0, 0, 0);
            sc[kt] = __builtin_amdgcn_mfma_f32_16x16x32_bf16(qf1, k1, sc[kt], 0, 0, 0);
        }
        if (it == qt) {
            int q0 = qbase + w * 16 + quad * 4;
#pragma unroll
            for (int kt = 0; kt < 4; ++kt) {
                int kv = qbase + kt * 16 + ln;
#pragma unroll
                for (int r = 0; r < 4; ++r)
                    if (kv > q0 + r) sc[kt][r] = -1e30f;
            }
        }
#pragma unroll
        for (int kt = 0; kt < 4; ++kt)
#pragma unroll
            for (int r = 0; r < 4; ++r)
                sc[kt][r] = exp2f(sc[kt][r] - SOFTMAX_OFF);

#pragma unroll
        for (int kt = 0; kt < 4; ++kt) {
            union { __hip_bfloat162 hh; unsigned int u; } p01, p23;
            p01.hh = __float22bfloat162_rn(make_float2(sc[kt][0], sc[kt][1]));
            p23.hh = __float22bfloat162_rn(make_float2(sc[kt][2], sc[kt][3]));
            P[w][quad * 4 + 0][kt * 16 + ln] = (unsigned short)p01.u;
            P[w][quad * 4 + 1][kt * 16 + ln] = (unsigned short)(p01.u >> 16);
            P[w][quad * 4 + 2][kt * 16 + ln] = (unsigned short)p23.u;
            P[w][quad * 4 + 3][kt * 16 + ln] = (unsigned short)(p23.u >> 16);
        }
        LDS_FENCE();
        v8s pf0 = *(const v8s*)&P[w][ln][quad * 8];
        v8s pf1 = *(const v8s*)&P[w][ln][quad * 8 + 32];
        LDS_FENCE();
#pragma unroll
        for (int dt = 0; dt < 4; ++dt) {
            int row = dt * 16 + ln;
            v8s v0 = *(const v8s*)&Vb[buf][row * 64 + c0];
            v8s v1 = *(const v8s*)&Vb[buf][row * 64 + c1];
            oacc[dt] = __builtin_amdgcn_mfma_f32_16x16x32_bf16(pf0, v0, oacc[dt], 0, 0, 0);
            oacc[dt] = __builtin_amdgcn_mfma_f32_16x16x32_bf16(pf1, v1, oacc[dt], 0, 0, 0);
        }
        oacc[4] = __builtin_amdgcn_mfma_f32_16x16x32_bf16(pf0, ones, oacc[4], 0, 0, 0);
        oacc[4] = __builtin_amdgcn_mfma_f32_16x16x32_bf16(pf1, ones, oacc[4], 0, 0, 0);
    };

    stage(0, 0);
    int it = 0;
    for (;;) {
        __syncthreads();
        stage(1, (it + 1) * 64);
        compute(0, it);
        if (++it >= nit) break;
        __syncthreads();
        stage(0, (it + 1) * 64);
        compute(1, it);
        if (++it >= nit) break;
    }

    float rden[4];
#pragma unroll
    for (int r = 0; r < 4; ++r) rden[r] = 1.f / oacc[4][r];
#pragma unroll
    for (int dt = 0; dt < 4; ++dt)
#pragma unroll
        for (int r = 0; r < 4; ++r) {
            int s = qbase + w * 16 + quad * 4 + r;
            Og[(size_t)(b * 2048 + s) * 1024 + h * 64 + dt * 16 + ln] =
                f2bf(oacc[dt][r] * rden[r]);
        }
}

extern "C" void kernel_launch(void* const* d_in, const int* in_sizes, int n_in,
                              void* d_out, int out_size, void* d_ws, size_t ws_size,
                              hipStream_t stream) {
    const float* x     = (const float*)d_in[0];
    const float* w_qkv = (const float*)d_in[2];
    const float* w_out = (const float*)d_in[3];
    char* ws = (char*)d_ws;

    unsigned short* xb    = (unsigned short*)(ws);                      //  8 MB
    unsigned short* wqkvT = (unsigned short*)(ws + (size_t)(8 << 20));  //  6 MB
    unsigned short* woutT = (unsigned short*)(ws + (size_t)(14 << 20)); //  2 MB
    unsigned short* Qg    = (unsigned short*)(ws + (size_t)(16 << 20)); //  8 MB
    unsigned short* Kg    = (unsigned short*)(ws + (size_t)(24 << 20)); //  8 MB (flash K over-prefetch -> Vt, read-only)
    unsigned short* Vt    = (unsigned short*)(ws + (size_t)(32 << 20)); //  8 MB (flash V over-prefetch -> Og, read-only)
    unsigned short* Og    = (unsigned short*)(ws + (size_t)(40 << 20)); //  8 MB
    float2*         rope  = (float2*)(ws + (size_t)(48 << 20));         // 512 KB

    k_prep<<<2304, 256, 0, stream>>>(x, w_qkv, w_out, xb, wqkvT, woutT, rope);
    k_gemm_qkv<<<dim3(24, 32), 256, 0, stream>>>(xb, wqkvT, rope, Qg, Kg, Vt);
    k_flash<<<1024, 256, 0, stream>>>(Qg, Kg, Vt, Og);
    k_gemm_out<<<dim3(8, 32), 256, 0, stream>>>(Og, woutT, (float*)d_out);
}